// Round 2
// baseline (375.794 us; speedup 1.0000x reference)
//
#include <hip/hip_runtime.h>
#include <hip/hip_bf16.h>
#include <math.h>

// Problem constants
#define NB   32
#define CIN  256
#define HH   64
#define WW   64
#define ICK  768     // 3*CIN
#define MIPC 8
#define PP   128     // h + w

__device__ __forceinline__ float sigmoidf_(float v) {
    return 1.0f / (1.0f + expf(-v));
}

// ---------------- Kernel 1: pooled stats -> yin[n][768][128] ----------------
// block per (n, c). Loads 64x64 f32 tile, computes row half-sums and column
// half-sums, writes the 6 pooled groups in conv-input layout.
__global__ void k1_pool(const float* __restrict__ x, float* __restrict__ yin) {
    const int n = blockIdx.x >> 8;
    const int c = blockIdx.x & 255;
    __shared__ float tile[64][65];   // +1 pad: conflict-free column reads
    __shared__ float rs[64][2];      // row half-sums (w<32, w>=32)
    __shared__ float cs[2][64];      // col half-sums (h<32, h>=32)

    const int t = threadIdx.x;
    const float* xb = x + ((size_t)(n * CIN + c) << 12);   // 4096 floats

    const float4* x4 = (const float4*)xb;
#pragma unroll
    for (int i = 0; i < 4; ++i) {
        int idx  = i * 256 + t;        // float4 index 0..1023
        int row  = idx >> 4;
        int col4 = idx & 15;
        float4 v = x4[idx];
        tile[row][col4 * 4 + 0] = v.x;
        tile[row][col4 * 4 + 1] = v.y;
        tile[row][col4 * 4 + 2] = v.z;
        tile[row][col4 * 4 + 3] = v.w;
    }
    __syncthreads();

    if (t < 128) {
        int r = t >> 1, half = t & 1;
        float s = 0.f;
#pragma unroll
        for (int j = 0; j < 32; ++j) s += tile[r][half * 32 + j];
        rs[r][half] = s;
    } else {
        int t2 = t - 128;
        int w = t2 & 63, hh = t2 >> 6;
        float s = 0.f;
#pragma unroll
        for (int j = 0; j < 32; ++j) s += tile[hh * 32 + j][w];
        cs[hh][w] = s;
    }
    __syncthreads();

    if (t < 128) {
        int p = t;
        float g1, g2;
        if (p < 64) { g1 = rs[p][0];      g2 = rs[p][1]; }
        else        { g1 = cs[0][p - 64]; g2 = cs[1][p - 64]; }
        float g0 = (g1 + g2) * (1.f / 64.f);
        float* yb = yin + ((size_t)n * ICK + c) * PP + p;
        yb[0]                      = g0;
        yb[(size_t)256 * PP]       = g1 * (1.f / 32.f);
        yb[(size_t)512 * PP]       = g2 * (1.f / 32.f);
    }
}

// ---- Kernel 2a: 1-D dilated conv (center kw tap only) + BN + SiLU + mean ----
// block per (n, o): o in [0,8). Output ysilu[n][8][128], semean[n][8].
__global__ void k2a_conv(const float* __restrict__ yin,
                         const float* __restrict__ w1, const float* __restrict__ b1,
                         const float* __restrict__ gamma, const float* __restrict__ beta,
                         const float* __restrict__ bmean, const float* __restrict__ bvar,
                         float* __restrict__ ysilu, float* __restrict__ semean) {
    const int n = blockIdx.x >> 3;
    const int o = blockIdx.x & 7;
    const int t = threadIdx.x;

    __shared__ float Wl[ICK * 3];        // 9.2 KB: W'[ic][kh] = w1[o][ic][kh][1]
    __shared__ float ylds[64][132];      // 33.8 KB: padded chunk (2 zeros each side)
    __shared__ float part[2][128];
    __shared__ float red[4];

    // weights: only the kw=1 column of the 3x3 kernel is ever in-bounds
    for (int i = t; i < ICK * 3; i += 256) {
        int ic = i / 3, kh = i - ic * 3;
        Wl[i] = w1[(size_t)o * (ICK * 9) + (size_t)ic * 9 + kh * 3 + 1];
    }
    // zero the pad columns once (q = 0,1,130,131)
    {
        int i = t >> 2, e = t & 3;
        int q = (e < 2) ? e : (e + 128);
        ylds[i][q] = 0.f;
    }

    const int p   = t & 127;
    const int rep = t >> 7;
    float acc = 0.f;

    for (int ic0 = 0; ic0 < ICK; ic0 += 64) {
        __syncthreads();
        for (int idx = t; idx < 64 * 128; idx += 256) {
            int i = idx >> 7, pp = idx & 127;
            ylds[i][pp + 2] = yin[((size_t)n * ICK + ic0 + i) * PP + pp];
        }
        __syncthreads();
        const int ib = rep * 32;
#pragma unroll
        for (int i = ib; i < ib + 32; ++i) {
            const float* wr = &Wl[(ic0 + i) * 3];
            acc += wr[0] * ylds[i][p]
                 + wr[1] * ylds[i][p + 2]
                 + wr[2] * ylds[i][p + 4];
        }
    }

    part[rep][p] = acc;
    __syncthreads();

    float s = 0.f;
    if (t < 128) {
        float tot = part[0][t] + part[1][t];
        float scale = gamma[o] * rsqrtf(bvar[o] + 1e-5f);
        float v = (tot + b1[o] - bmean[o]) * scale + beta[o];
        s = v * sigmoidf_(v);
        ysilu[((size_t)n * MIPC + o) * PP + t] = s;
    }
    // reduce sum(s) over the 128 active threads (waves 0,1)
    float v = s;
#pragma unroll
    for (int off = 32; off; off >>= 1) v += __shfl_down(v, off);
    if ((t & 63) == 0) red[t >> 6] = v;
    __syncthreads();
    if (t == 0) semean[n * MIPC + o] = (red[0] + red[1]) * (1.f / 128.f);
}

// -------- Kernel 2b: SE gate + head GEMVs -> a_h[n][256][64], a_w --------
__global__ void k2b_heads(const float* __restrict__ ysilu, const float* __restrict__ semean,
                          const float* __restrict__ gw, const float* __restrict__ gb,
                          const float* __restrict__ chw, const float* __restrict__ chb,
                          const float* __restrict__ cww, const float* __restrict__ cwb,
                          float* __restrict__ a_h, float* __restrict__ a_w) {
    const int n = blockIdx.x;
    const int t = threadIdx.x;
    __shared__ float yf[MIPC][PP];
    __shared__ float se[MIPC];

    if (t < MIPC) {
        float m = semean[n * MIPC + t];
        se[t] = sigmoidf_(gw[0] * m + gb[0]);
    }
    __syncthreads();
    for (int idx = t; idx < MIPC * PP; idx += 256) {
        int m = idx >> 7, p = idx & 127;
        yf[m][p] = ysilu[((size_t)n * MIPC + m) * PP + p] * se[m];
    }
    __syncthreads();

    for (int iter = 0; iter < 64; ++iter) {
        int idx = iter * 256 + t;          // 16384 items
        int oc = idx >> 6, h = idx & 63;
        float acch = chb[oc], accw = cwb[oc];
#pragma unroll
        for (int m = 0; m < MIPC; ++m) {
            float wh = chw[oc * MIPC + m];
            float wwv = cww[oc * MIPC + m];
            acch += wh  * yf[m][h];
            accw += wwv * yf[m][64 + h];
        }
        size_t base = ((size_t)n * CIN + oc) * 64 + h;
        a_h[base] = sigmoidf_(acch);
        a_w[base] = sigmoidf_(accw);
    }
}

// ---------------- Kernel 3: out = x * a_h[h] * a_w[w] ----------------
__global__ void k3_apply(const float* __restrict__ x,
                         const float* __restrict__ a_h, const float* __restrict__ a_w,
                         float* __restrict__ out) {
    const int n = blockIdx.x >> 8;
    const int c = blockIdx.x & 255;
    const int t = threadIdx.x;
    __shared__ float ah[64];
    __shared__ float aw[64];

    size_t abase = ((size_t)(n * CIN + c)) * 64;
    if (t < 64)       ah[t]      = a_h[abase + t];
    else if (t < 128) aw[t - 64] = a_w[abase + (t - 64)];
    __syncthreads();

    size_t base = ((size_t)(n * CIN + c)) << 12;
    const float4* x4 = (const float4*)(x + base);
    float4* o4 = (float4*)(out + base);
    const float4* aw4 = (const float4*)aw;
#pragma unroll
    for (int i = 0; i < 4; ++i) {
        int idx  = i * 256 + t;
        int row  = idx >> 4;
        int col4 = idx & 15;
        float4 v = x4[idx];
        float a = ah[row];
        float4 wv = aw4[col4];
        v.x *= a * wv.x;
        v.y *= a * wv.y;
        v.z *= a * wv.z;
        v.w *= a * wv.w;
        o4[idx] = v;
    }
}

extern "C" void kernel_launch(void* const* d_in, const int* in_sizes, int n_in,
                              void* d_out, int out_size, void* d_ws, size_t ws_size,
                              hipStream_t stream) {
    const float* x     = (const float*)d_in[0];
    const float* w1    = (const float*)d_in[1];
    const float* b1    = (const float*)d_in[2];
    const float* gamma = (const float*)d_in[3];
    const float* beta  = (const float*)d_in[4];
    const float* bmean = (const float*)d_in[5];
    const float* bvar  = (const float*)d_in[6];
    const float* gw    = (const float*)d_in[7];
    const float* gb    = (const float*)d_in[8];
    const float* chw   = (const float*)d_in[9];
    const float* chb   = (const float*)d_in[10];
    const float* cww   = (const float*)d_in[11];
    const float* cwb   = (const float*)d_in[12];
    float* out = (float*)d_out;

    float* ws    = (float*)d_ws;
    float* yin   = ws;                         // 32*768*128      = 3,145,728 f
    float* ysilu = yin + (size_t)NB * ICK * PP;        // 32*8*128 = 32,768 f
    float* sem   = ysilu + (size_t)NB * MIPC * PP;     // 256 f
    float* ah    = sem + NB * MIPC;                    // 32*256*64 = 524,288 f
    float* aw    = ah + (size_t)NB * CIN * 64;         // 524,288 f

    k1_pool <<<NB * CIN, 256, 0, stream>>>(x, yin);
    k2a_conv<<<NB * MIPC, 256, 0, stream>>>(yin, w1, b1, gamma, beta, bmean, bvar,
                                            ysilu, sem);
    k2b_heads<<<NB, 256, 0, stream>>>(ysilu, sem, gw, gb, chw, chb, cww, cwb, ah, aw);
    k3_apply<<<NB * CIN, 256, 0, stream>>>(x, ah, aw, out);
}

// Round 3
// 300.620 us; speedup vs baseline: 1.2501x; 1.2501x over previous
//
#include <hip/hip_runtime.h>
#include <hip/hip_bf16.h>
#include <math.h>

// Problem constants
#define NB   32
#define CIN  256
#define HH   64
#define WW   64
#define ICK  768     // 3*CIN
#define MIPC 8
#define PP   128     // h + w

__device__ __forceinline__ float sigmoidf_(float v) {
    return 1.0f / (1.0f + expf(-v));
}

// ---------------- Kernel 1: pooled stats -> yin[n][768][128] ----------------
// block per (n, c). Loads 64x64 f32 tile, computes row half-sums and column
// half-sums, writes the 6 pooled groups in conv-input layout.
__global__ void k1_pool(const float* __restrict__ x, float* __restrict__ yin) {
    const int n = blockIdx.x >> 8;
    const int c = blockIdx.x & 255;
    __shared__ float tile[64][65];   // +1 pad: conflict-free column reads
    __shared__ float rs[64][2];      // row half-sums (w<32, w>=32)
    __shared__ float cs[2][64];      // col half-sums (h<32, h>=32)

    const int t = threadIdx.x;
    const float* xb = x + ((size_t)(n * CIN + c) << 12);   // 4096 floats

    const float4* x4 = (const float4*)xb;
#pragma unroll
    for (int i = 0; i < 4; ++i) {
        int idx  = i * 256 + t;        // float4 index 0..1023
        int row  = idx >> 4;
        int col4 = idx & 15;
        float4 v = x4[idx];
        tile[row][col4 * 4 + 0] = v.x;
        tile[row][col4 * 4 + 1] = v.y;
        tile[row][col4 * 4 + 2] = v.z;
        tile[row][col4 * 4 + 3] = v.w;
    }
    __syncthreads();

    if (t < 128) {
        int r = t >> 1, half = t & 1;
        float s = 0.f;
#pragma unroll
        for (int j = 0; j < 32; ++j) s += tile[r][half * 32 + j];
        rs[r][half] = s;
    } else {
        int t2 = t - 128;
        int w = t2 & 63, hh = t2 >> 6;
        float s = 0.f;
#pragma unroll
        for (int j = 0; j < 32; ++j) s += tile[hh * 32 + j][w];
        cs[hh][w] = s;
    }
    __syncthreads();

    if (t < 128) {
        int p = t;
        float g1, g2;
        if (p < 64) { g1 = rs[p][0];      g2 = rs[p][1]; }
        else        { g1 = cs[0][p - 64]; g2 = cs[1][p - 64]; }
        float g0 = (g1 + g2) * (1.f / 64.f);
        float* yb = yin + ((size_t)n * ICK + c) * PP + p;
        yb[0]                      = g0;
        yb[(size_t)256 * PP]       = g1 * (1.f / 32.f);
        yb[(size_t)512 * PP]       = g2 * (1.f / 32.f);
    }
}

// ---- Kernel 2a: partial 1-D dilated conv (center kw tap only) ----
// grid (n, o, chunk) = 32*8*8 = 2048 blocks. Each block: 96-IC partial sum
// for all 128 positions. partial[n][chunk][o][p].
__global__ void k2a_partial(const float* __restrict__ yin,
                            const float* __restrict__ w1,
                            float* __restrict__ partial) {
    const int b     = blockIdx.x;
    const int chunk = b & 7;
    const int o     = (b >> 3) & 7;
    const int n     = b >> 6;
    const int t     = threadIdx.x;

    __shared__ float Wl[96 * 3];
    __shared__ float part[2][128];

    // stage weights: kw=1 column of the 3x3 kernel only
    for (int i = t; i < 96 * 3; i += 256) {
        int icl = i / 3, kh = i - icl * 3;
        Wl[i] = w1[(size_t)o * (ICK * 9) + (size_t)(chunk * 96 + icl) * 9 + kh * 3 + 1];
    }
    __syncthreads();

    const int p   = t & 127;
    const int rep = t >> 7;
    const float* yb = yin + ((size_t)n * ICK + chunk * 96 + rep * 48) * PP;

    float acc = 0.f;
#pragma unroll 4
    for (int i = 0; i < 48; ++i) {
        const float* row = yb + (size_t)i * PP;
        const float* wr  = &Wl[(rep * 48 + i) * 3];
        float v0 = (p >= 2)   ? row[p - 2] : 0.f;
        float v1 = row[p];
        float v2 = (p < 126) ? row[p + 2] : 0.f;
        acc += wr[0] * v0 + wr[1] * v1 + wr[2] * v2;
    }

    part[rep][p] = acc;
    __syncthreads();
    if (t < 128) {
        partial[(((size_t)n * 8 + chunk) * 8 + o) * PP + t] = part[0][t] + part[1][t];
    }
}

// ---- Kernel 2r: reduce partials + BN + SiLU + SE mean/gate -> gated ysilu ----
// block per n (32 blocks).
__global__ void k2r_reduce(const float* __restrict__ partial,
                           const float* __restrict__ b1,
                           const float* __restrict__ gamma, const float* __restrict__ beta,
                           const float* __restrict__ bmean, const float* __restrict__ bvar,
                           const float* __restrict__ gw, const float* __restrict__ gb,
                           float* __restrict__ ysilu) {
    const int n = blockIdx.x;
    const int t = threadIdx.x;
    __shared__ float sm[8][129];   // +1 pad: conflict-free column sums
    __shared__ float seg[8];

    float sv[4];
#pragma unroll
    for (int k = 0; k < 4; ++k) {
        int idx = k * 256 + t;
        int o = idx >> 7, p = idx & 127;
        float s = 0.f;
#pragma unroll
        for (int ch = 0; ch < 8; ++ch)
            s += partial[(((size_t)n * 8 + ch) * 8 + o) * PP + p];
        float scale = gamma[o] * rsqrtf(bvar[o] + 1e-5f);
        float v = (s + b1[o] - bmean[o]) * scale + beta[o];
        float sl = v * sigmoidf_(v);
        sv[k] = sl;
        sm[o][p] = sl;
    }
    __syncthreads();
    if (t < 8) {
        float s = 0.f;
#pragma unroll
        for (int p = 0; p < 128; ++p) s += sm[t][p];
        seg[t] = sigmoidf_(gw[0] * (s * (1.f / 128.f)) + gb[0]);
    }
    __syncthreads();
#pragma unroll
    for (int k = 0; k < 4; ++k) {
        int idx = k * 256 + t;
        int o = idx >> 7, p = idx & 127;
        ysilu[((size_t)n * MIPC + o) * PP + p] = sv[k] * seg[o];
    }
}

// -------- Kernel 2b: head GEMVs -> a_h[n][256][64], a_w[n][256][64] --------
// grid (n, oc-chunk of 32) = 256 blocks.
__global__ void k2b_heads(const float* __restrict__ ysilu,
                          const float* __restrict__ chw, const float* __restrict__ chb,
                          const float* __restrict__ cww, const float* __restrict__ cwb,
                          float* __restrict__ a_h, float* __restrict__ a_w) {
    const int n   = blockIdx.x >> 3;
    const int occ = blockIdx.x & 7;
    const int t   = threadIdx.x;
    __shared__ float yf[MIPC][PP];

    for (int i = t; i < MIPC * PP; i += 256)
        yf[i >> 7][i & 127] = ysilu[(size_t)n * MIPC * PP + i];
    __syncthreads();

#pragma unroll
    for (int k = 0; k < 8; ++k) {
        int idx = k * 256 + t;          // 2048 items: 32 oc x 64 h
        int oc  = occ * 32 + (idx >> 6);
        int h   = idx & 63;
        float acch = chb[oc], accw = cwb[oc];
#pragma unroll
        for (int m = 0; m < MIPC; ++m) {
            acch += chw[oc * MIPC + m] * yf[m][h];
            accw += cww[oc * MIPC + m] * yf[m][64 + h];
        }
        size_t base = ((size_t)n * CIN + oc) * 64 + h;
        a_h[base] = sigmoidf_(acch);
        a_w[base] = sigmoidf_(accw);
    }
}

// ---------------- Kernel 3: out = x * a_h[h] * a_w[w] ----------------
__global__ void k3_apply(const float* __restrict__ x,
                         const float* __restrict__ a_h, const float* __restrict__ a_w,
                         float* __restrict__ out) {
    const int n = blockIdx.x >> 8;
    const int c = blockIdx.x & 255;
    const int t = threadIdx.x;
    __shared__ float ah[64];
    __shared__ float aw[64];

    size_t abase = ((size_t)(n * CIN + c)) * 64;
    if (t < 64)       ah[t]      = a_h[abase + t];
    else if (t < 128) aw[t - 64] = a_w[abase + (t - 64)];
    __syncthreads();

    size_t base = ((size_t)(n * CIN + c)) << 12;
    const float4* x4 = (const float4*)(x + base);
    float4* o4 = (float4*)(out + base);
    const float4* aw4 = (const float4*)aw;
#pragma unroll
    for (int i = 0; i < 4; ++i) {
        int idx  = i * 256 + t;
        int row  = idx >> 4;
        int col4 = idx & 15;
        float4 v = x4[idx];
        float a = ah[row];
        float4 wv = aw4[col4];
        v.x *= a * wv.x;
        v.y *= a * wv.y;
        v.z *= a * wv.z;
        v.w *= a * wv.w;
        o4[idx] = v;
    }
}

extern "C" void kernel_launch(void* const* d_in, const int* in_sizes, int n_in,
                              void* d_out, int out_size, void* d_ws, size_t ws_size,
                              hipStream_t stream) {
    const float* x     = (const float*)d_in[0];
    const float* w1    = (const float*)d_in[1];
    const float* b1    = (const float*)d_in[2];
    const float* gamma = (const float*)d_in[3];
    const float* beta  = (const float*)d_in[4];
    const float* bmean = (const float*)d_in[5];
    const float* bvar  = (const float*)d_in[6];
    const float* gw    = (const float*)d_in[7];
    const float* gb    = (const float*)d_in[8];
    const float* chw   = (const float*)d_in[9];
    const float* chb   = (const float*)d_in[10];
    const float* cww   = (const float*)d_in[11];
    const float* cwb   = (const float*)d_in[12];
    float* out = (float*)d_out;

    float* ws      = (float*)d_ws;
    float* yin     = ws;                                   // 32*768*128 = 3,145,728 f
    float* partial = yin + (size_t)NB * ICK * PP;          // 32*8*8*128 = 262,144 f
    float* ysilu   = partial + (size_t)NB * 8 * MIPC * PP; // 32*8*128   = 32,768 f
    float* ah      = ysilu + (size_t)NB * MIPC * PP;       // 32*256*64  = 524,288 f
    float* aw      = ah + (size_t)NB * CIN * 64;           // 524,288 f

    k1_pool    <<<NB * CIN, 256, 0, stream>>>(x, yin);
    k2a_partial<<<NB * MIPC * 8, 256, 0, stream>>>(yin, w1, partial);
    k2r_reduce <<<NB, 256, 0, stream>>>(partial, b1, gamma, beta, bmean, bvar,
                                        gw, gb, ysilu);
    k2b_heads  <<<NB * 8, 256, 0, stream>>>(ysilu, chw, chb, cww, cwb, ah, aw);
    k3_apply   <<<NB * CIN, 256, 0, stream>>>(x, ah, aw, out);
}